// Round 1
// baseline (851.990 us; speedup 1.0000x reference)
//
#include <hip/hip_runtime.h>

typedef __attribute__((ext_vector_type(8))) short short8;
typedef __attribute__((ext_vector_type(4))) short short4v;
typedef __attribute__((ext_vector_type(4))) float f32x4;
typedef unsigned int u32;

#define AS1 __attribute__((address_space(1)))
#define AS3 __attribute__((address_space(3)))

__device__ __forceinline__ short f2bf(float x){
  union { float f; u32 u; } v; v.f = x;
  u32 r = (v.u + 0x7FFFu + ((v.u >> 16) & 1u)) >> 16;   // RNE
  return (short)r;
}
__device__ __forceinline__ float bf2f(short s){
  union { u32 u; float f; } v; v.u = ((u32)(unsigned short)s) << 16;
  return v.f;
}
__device__ __forceinline__ void gload16(const void* src, void* dst){
  __builtin_amdgcn_global_load_lds((const AS1 u32*)src, (AS3 u32*)dst, 16, 0, 0);
}

// ---------------- converts ----------------
__global__ __launch_bounds__(256) void cvt_x_kernel(const float* __restrict__ x, short* __restrict__ xb){
  int i = blockIdx.x * 256 + threadIdx.x;   // one group of 8 elems per thread
  if (i >= 2097152) return;
  const float4* xf = (const float4*)x;
  float4 a = xf[2*i], b = xf[2*i+1];
  short8 o;
  o[0]=f2bf(a.x); o[1]=f2bf(a.y); o[2]=f2bf(a.z); o[3]=f2bf(a.w);
  o[4]=f2bf(b.x); o[5]=f2bf(b.y); o[6]=f2bf(b.z); o[7]=f2bf(b.w);
  ((short8*)xb)[i] = o;
}

// transpose-convert W [K=1024][N=1024] f32 -> Wt [N][K] bf16, z selects q/k/v
__global__ __launch_bounds__(256) void cvt_w_kernel(const float* __restrict__ Wq, const float* __restrict__ Wk,
                                                    const float* __restrict__ Wv, short* __restrict__ Wt){
  __shared__ float tile[32][33];
  const float* W = blockIdx.z == 0 ? Wq : (blockIdx.z == 1 ? Wk : Wv);
  short* out = Wt + (size_t)blockIdx.z * 1024 * 1024;
  int n0 = blockIdx.x * 32, k0 = blockIdx.y * 32;
  int tx = threadIdx.x, ty = threadIdx.y;
  #pragma unroll
  for (int i=0;i<4;i++) tile[ty + 8*i][tx] = W[(size_t)(k0 + ty + 8*i) * 1024 + n0 + tx];
  __syncthreads();
  #pragma unroll
  for (int i=0;i<4;i++) out[(size_t)(n0 + ty + 8*i) * 1024 + k0 + tx] = f2bf(tile[tx][ty + 8*i]);
}

// ---------------- BT-form bf16 GEMM: C[m][n] = sum_k A[m][k] * B[n][k] ----------------
// 128x128 tile, BK=64, 256 threads (4 waves in 2x2), mfma_f32_16x16x32_bf16
// EPI: 0 = bf16 out + bias (q/k; z selects bias0/bias1, C += z*cbst)
//      1 = bf16 TRANSPOSED out + bias (v -> vt[b][n][m])
//      2 = bf16 out, scaled (scores)
//      3 = f32 out (PV -> d_out)
template<int EPI>
__global__ __launch_bounds__(256)
void gemm_bt(const short* __restrict__ A, int lda, long abst,
             const short* __restrict__ B, int ldb, long bbst,
             void* __restrict__ Cv, long cbst,
             const float* __restrict__ bias0, const float* __restrict__ bias1,
             int M, int N, int K, float scale)
{
  __shared__ alignas(16) short As[128*64];
  __shared__ alignas(16) short Bs[128*64];
  const int z = blockIdx.z;
  A += (size_t)z * abst;
  B += (size_t)z * bbst;
  const int m0 = blockIdx.x * 128, n0 = blockIdx.y * 128;
  const int t = threadIdx.x, w = t >> 6, l = t & 63;
  const int wr = w >> 1, wc = w & 1;
  const int lr = l & 15, lk = (l >> 4) * 8;

  f32x4 acc[4][4];
  #pragma unroll
  for (int i=0;i<4;i++)
    #pragma unroll
    for (int j=0;j<4;j++) acc[i][j] = (f32x4){0.f,0.f,0.f,0.f};

  const int r0 = t >> 3;              // staging: chunk c = i*256+t, row = i*32 + (t>>3)
  const int cb = (t & 7) * 16;        // byte col within 128B row
  const char* Ab = (const char*)A;
  const char* Bb = (const char*)B;
  const size_t lda2 = (size_t)lda * 2, ldb2 = (size_t)ldb * 2;

  for (int kt = 0; kt < K; kt += 64){
    #pragma unroll
    for (int i=0;i<4;i++){
      int row = i*32 + r0;
      int ldsoff = (i*256 + w*64) * 16;
      gload16(Ab + (size_t)(m0 + row) * lda2 + (size_t)kt*2 + cb, (char*)As + ldsoff);
      gload16(Bb + (size_t)(n0 + row) * ldb2 + (size_t)kt*2 + cb, (char*)Bs + ldsoff);
    }
    __syncthreads();
    #pragma unroll
    for (int ks=0; ks<2; ks++){
      short8 fa[4], fb[4];
      #pragma unroll
      for (int i=0;i<4;i++){
        fa[i] = *(const short8*)&As[(wr*64 + i*16 + lr)*64 + ks*32 + lk];
        fb[i] = *(const short8*)&Bs[(wc*64 + i*16 + lr)*64 + ks*32 + lk];
      }
      #pragma unroll
      for (int i=0;i<4;i++)
        #pragma unroll
        for (int j=0;j<4;j++)
          acc[i][j] = __builtin_amdgcn_mfma_f32_16x16x32_bf16(fa[i], fb[j], acc[i][j], 0, 0, 0);
    }
    __syncthreads();
  }

  // epilogue: C/D layout col = lane&15, row = (lane>>4)*4 + reg  [m89/m91]
  const int mw = m0 + wr*64 + ((l >> 4) << 2);
  const int nw = n0 + wc*64 + lr;

  if constexpr (EPI == 0){
    const float* bias = z ? bias1 : bias0;
    short* C = (short*)Cv + (size_t)z * cbst;
    float bvv[4];
    #pragma unroll
    for (int j=0;j<4;j++) bvv[j] = bias[nw + j*16];
    #pragma unroll
    for (int i=0;i<4;i++){
      int m = mw + i*16;
      #pragma unroll
      for (int j=0;j<4;j++){
        int n = nw + j*16;
        #pragma unroll
        for (int r=0;r<4;r++)
          C[(size_t)(m+r)*N + n] = f2bf(acc[i][j][r] + bvv[j]);
      }
    }
  } else if constexpr (EPI == 1){
    short* C = (short*)Cv;                     // vt[b][n][m_local], S=2048, D=1024
    float bvv[4];
    #pragma unroll
    for (int j=0;j<4;j++) bvv[j] = bias0[nw + j*16];
    #pragma unroll
    for (int i=0;i<4;i++){
      int m = mw + i*16;
      int bidx = m >> 11, ml = m & 2047;
      #pragma unroll
      for (int j=0;j<4;j++){
        int n = nw + j*16;
        short4v pk;
        #pragma unroll
        for (int r=0;r<4;r++) pk[r] = f2bf(acc[i][j][r] + bvv[j]);
        *(short4v*)&C[((size_t)(bidx*1024 + n)) * 2048 + ml] = pk;
      }
    }
  } else if constexpr (EPI == 2){
    short* C = (short*)Cv;
    #pragma unroll
    for (int i=0;i<4;i++){
      int m = mw + i*16;
      #pragma unroll
      for (int j=0;j<4;j++){
        int n = nw + j*16;
        #pragma unroll
        for (int r=0;r<4;r++)
          C[(size_t)(m+r)*N + n] = f2bf(acc[i][j][r] * scale);
      }
    }
  } else {
    float* C = (float*)Cv;
    #pragma unroll
    for (int i=0;i<4;i++){
      int m = mw + i*16;
      #pragma unroll
      for (int j=0;j<4;j++){
        int n = nw + j*16;
        #pragma unroll
        for (int r=0;r<4;r++)
          C[(size_t)(m+r)*N + n] = acc[i][j][r];
      }
    }
  }
}

// ---------------- row softmax, in-place on bf16 scores [rows][2048] ----------------
__global__ __launch_bounds__(256) void softmax_kernel(short* __restrict__ S){
  const int row = blockIdx.x;
  short* p = S + (size_t)row * 2048;
  const int t = threadIdx.x, w = t >> 6, l = t & 63;
  short8 v = *(short8*)&p[t*8];
  float f[8];
  #pragma unroll
  for (int i=0;i<8;i++) f[i] = bf2f(v[i]);
  float mx = f[0];
  #pragma unroll
  for (int i=1;i<8;i++) mx = fmaxf(mx, f[i]);
  #pragma unroll
  for (int off=32; off>=1; off>>=1) mx = fmaxf(mx, __shfl_xor(mx, off));
  __shared__ float rmax[4], rsum[4];
  if (l == 0) rmax[w] = mx;
  __syncthreads();
  mx = fmaxf(fmaxf(rmax[0], rmax[1]), fmaxf(rmax[2], rmax[3]));
  float e[8], s = 0.f;
  #pragma unroll
  for (int i=0;i<8;i++){ e[i] = __expf(f[i] - mx); s += e[i]; }
  #pragma unroll
  for (int off=32; off>=1; off>>=1) s += __shfl_xor(s, off);
  if (l == 0) rsum[w] = s;
  __syncthreads();
  s = rsum[0] + rsum[1] + rsum[2] + rsum[3];
  float inv = 1.0f / s;
  short8 o;
  #pragma unroll
  for (int i=0;i<8;i++) o[i] = f2bf(e[i] * inv);
  *(short8*)&p[t*8] = o;
}

// ---------------- launch ----------------
extern "C" void kernel_launch(void* const* d_in, const int* in_sizes, int n_in,
                              void* d_out, int out_size, void* d_ws, size_t ws_size,
                              hipStream_t stream){
  (void)in_sizes; (void)n_in; (void)out_size; (void)ws_size;
  const float* x  = (const float*)d_in[0];
  const float* Wq = (const float*)d_in[1];
  const float* bq = (const float*)d_in[2];
  const float* Wk = (const float*)d_in[3];
  const float* bk = (const float*)d_in[4];
  const float* Wv = (const float*)d_in[5];
  const float* bv = (const float*)d_in[6];
  float* out = (float*)d_out;
  char* ws = (char*)d_ws;

  // ws layout (bytes): total 148,897,792
  short* xb  = (short*)(ws + 0);           // x bf16            32 MB
  short* Wt  = (short*)(ws + 33554432);    // Wq/Wk/Wv^T bf16    6 MB
  short* qb  = (short*)(ws + 39845888);    // q bf16            32 MB
  short* kb  = (short*)(ws + 73400320);    // k bf16            32 MB
  short* vt  = (short*)(ws + 106954752);   // v^T bf16 [B][D][S] 32 MB
  short* S   = (short*)(ws + 140509184);   // per-batch scores   8 MB (reused)

  cvt_x_kernel<<<8192, 256, 0, stream>>>(x, xb);
  cvt_w_kernel<<<dim3(32,32,3), dim3(32,8), 0, stream>>>(Wq, Wk, Wv, Wt);

  // q and k: z in {0,1}
  gemm_bt<0><<<dim3(128,8,2), 256, 0, stream>>>(xb, 1024, 0L, Wt, 1024, 1048576L,
                                                qb, 16777216L, bq, bk, 16384, 1024, 1024, 1.f);
  // v, written transposed
  gemm_bt<1><<<dim3(128,8,1), 256, 0, stream>>>(xb, 1024, 0L, Wt + 2*1048576, 1024, 0L,
                                                vt, 0L, bv, nullptr, 16384, 1024, 1024, 1.f);
  for (int b = 0; b < 8; b++){
    // scores = q_b @ k_b^T * (1/32) -> bf16
    gemm_bt<2><<<dim3(16,16,1), 256, 0, stream>>>(qb + (size_t)b*2097152, 1024, 0L,
                                                  kb + (size_t)b*2097152, 1024, 0L,
                                                  S, 0L, nullptr, nullptr, 2048, 2048, 1024, 0.03125f);
    softmax_kernel<<<2048, 256, 0, stream>>>(S);
    // out_b = P @ v_b  (BT-form against vt)
    gemm_bt<3><<<dim3(16,8,1), 256, 0, stream>>>(S, 2048, 0L,
                                                 vt + (size_t)b*2097152, 2048, 0L,
                                                 out + (size_t)b*2097152, 0L, nullptr, nullptr, 2048, 1024, 2048, 1.f);
  }
}

// Round 4
// 512.838 us; speedup vs baseline: 1.6613x; 1.6613x over previous
//
#include <hip/hip_runtime.h>

typedef __attribute__((ext_vector_type(8))) short short8;
typedef __attribute__((ext_vector_type(4))) short short4v;
typedef __attribute__((ext_vector_type(4))) float f32x4;
typedef unsigned int u32;

#define AS1 __attribute__((address_space(1)))
#define AS3 __attribute__((address_space(3)))

__device__ __forceinline__ short f2bf(float x){
  union { float f; u32 u; } v; v.f = x;
  u32 r = (v.u + 0x7FFFu + ((v.u >> 16) & 1u)) >> 16;   // RNE
  return (short)r;
}
__device__ __forceinline__ float bf2f(short s){
  union { u32 u; float f; } v; v.u = ((u32)(unsigned short)s) << 16;
  return v.f;
}
__device__ __forceinline__ void gload16(const void* src, void* dst){
  __builtin_amdgcn_global_load_lds((const AS1 u32*)src, (AS3 u32*)dst, 16, 0, 0);
}

// ---------------- converts ----------------
__global__ __launch_bounds__(256) void cvt_x_kernel(const float* __restrict__ x, short* __restrict__ xb){
  int i = blockIdx.x * 256 + threadIdx.x;
  if (i >= 2097152) return;
  const float4* xf = (const float4*)x;
  float4 a = xf[2*i], b = xf[2*i+1];
  short8 o;
  o[0]=f2bf(a.x); o[1]=f2bf(a.y); o[2]=f2bf(a.z); o[3]=f2bf(a.w);
  o[4]=f2bf(b.x); o[5]=f2bf(b.y); o[6]=f2bf(b.z); o[7]=f2bf(b.w);
  ((short8*)xb)[i] = o;
}

// transpose-convert W [K=1024][N=1024] f32 -> Wt [N][K] bf16, z selects q/k/v
__global__ __launch_bounds__(256) void cvt_w_kernel(const float* __restrict__ Wq, const float* __restrict__ Wk,
                                                    const float* __restrict__ Wv, short* __restrict__ Wt){
  __shared__ float tile[32][33];
  const float* W = blockIdx.z == 0 ? Wq : (blockIdx.z == 1 ? Wk : Wv);
  short* out = Wt + (size_t)blockIdx.z * 1024 * 1024;
  int n0 = blockIdx.x * 32, k0 = blockIdx.y * 32;
  int tx = threadIdx.x, ty = threadIdx.y;
  #pragma unroll
  for (int i=0;i<4;i++) tile[ty + 8*i][tx] = W[(size_t)(k0 + ty + 8*i) * 1024 + n0 + tx];
  __syncthreads();
  #pragma unroll
  for (int i=0;i<4;i++) out[(size_t)(n0 + ty + 8*i) * 1024 + k0 + tx] = f2bf(tile[tx][ty + 8*i]);
}

// ---------------- BT-form bf16 GEMM: C[m][n] = sum_k A[m][k] * B[n][k] ----------------
// 128x128 tile, BK=64, 256 threads (4 waves in 2x2), mfma_f32_16x16x32_bf16
// EPI: 0 = bf16 out + bias (q/k; z selects bias0/bias1)
//      1 = bf16 TRANSPOSED out + bias (v -> vt[b][n][m])
//      2 = bf16 out, scaled (scores)
//      3 = f32 out (PV -> d_out)
// All epilogues offset C by z*cbst (elements).
template<int EPI>
__global__ __launch_bounds__(256)
void gemm_bt(const short* __restrict__ A, int lda, long abst,
             const short* __restrict__ B, int ldb, long bbst,
             void* __restrict__ Cv, long cbst,
             const float* __restrict__ bias0, const float* __restrict__ bias1,
             int M, int N, int K, float scale)
{
  __shared__ alignas(16) short As[128*64];
  __shared__ alignas(16) short Bs[128*64];
  const int z = blockIdx.z;
  A += (size_t)z * abst;
  B += (size_t)z * bbst;
  const int m0 = blockIdx.x * 128, n0 = blockIdx.y * 128;
  const int t = threadIdx.x, w = t >> 6, l = t & 63;
  const int wr = w >> 1, wc = w & 1;
  const int lr = l & 15, lk = (l >> 4) * 8;

  f32x4 acc[4][4];
  #pragma unroll
  for (int i=0;i<4;i++)
    #pragma unroll
    for (int j=0;j<4;j++) acc[i][j] = (f32x4){0.f,0.f,0.f,0.f};

  const int r0 = t >> 3;
  const int cb = (t & 7) * 16;
  const char* Ab = (const char*)A;
  const char* Bb = (const char*)B;
  const size_t lda2 = (size_t)lda * 2, ldb2 = (size_t)ldb * 2;

  for (int kt = 0; kt < K; kt += 64){
    #pragma unroll
    for (int i=0;i<4;i++){
      int row = i*32 + r0;
      int ldsoff = (i*256 + w*64) * 16;
      gload16(Ab + (size_t)(m0 + row) * lda2 + (size_t)kt*2 + cb, (char*)As + ldsoff);
      gload16(Bb + (size_t)(n0 + row) * ldb2 + (size_t)kt*2 + cb, (char*)Bs + ldsoff);
    }
    __syncthreads();
    #pragma unroll
    for (int ks=0; ks<2; ks++){
      short8 fa[4], fb[4];
      #pragma unroll
      for (int i=0;i<4;i++){
        fa[i] = *(const short8*)&As[(wr*64 + i*16 + lr)*64 + ks*32 + lk];
        fb[i] = *(const short8*)&Bs[(wc*64 + i*16 + lr)*64 + ks*32 + lk];
      }
      #pragma unroll
      for (int i=0;i<4;i++)
        #pragma unroll
        for (int j=0;j<4;j++)
          acc[i][j] = __builtin_amdgcn_mfma_f32_16x16x32_bf16(fa[i], fb[j], acc[i][j], 0, 0, 0);
    }
    __syncthreads();
  }

  // epilogue: C/D layout col = lane&15, row = (lane>>4)*4 + reg  [m89/m91]
  const int mw = m0 + wr*64 + ((l >> 4) << 2);
  const int nw = n0 + wc*64 + lr;

  if constexpr (EPI == 0){
    const float* bias = z ? bias1 : bias0;
    short* C = (short*)Cv + (size_t)z * cbst;
    float bvv[4];
    #pragma unroll
    for (int j=0;j<4;j++) bvv[j] = bias[nw + j*16];
    #pragma unroll
    for (int i=0;i<4;i++){
      int m = mw + i*16;
      #pragma unroll
      for (int j=0;j<4;j++){
        int n = nw + j*16;
        #pragma unroll
        for (int r=0;r<4;r++)
          C[(size_t)(m+r)*N + n] = f2bf(acc[i][j][r] + bvv[j]);
      }
    }
  } else if constexpr (EPI == 1){
    short* C = (short*)Cv;                     // vt[b][n][m_local], S=2048, D=1024
    float bvv[4];
    #pragma unroll
    for (int j=0;j<4;j++) bvv[j] = bias0[nw + j*16];
    #pragma unroll
    for (int i=0;i<4;i++){
      int m = mw + i*16;
      int bidx = m >> 11, ml = m & 2047;
      #pragma unroll
      for (int j=0;j<4;j++){
        int n = nw + j*16;
        short4v pk;
        #pragma unroll
        for (int r=0;r<4;r++) pk[r] = f2bf(acc[i][j][r] + bvv[j]);
        *(short4v*)&C[((size_t)(bidx*1024 + n)) * 2048 + ml] = pk;
      }
    }
  } else if constexpr (EPI == 2){
    short* C = (short*)Cv + (size_t)z * cbst;
    #pragma unroll
    for (int i=0;i<4;i++){
      int m = mw + i*16;
      #pragma unroll
      for (int j=0;j<4;j++){
        int n = nw + j*16;
        #pragma unroll
        for (int r=0;r<4;r++)
          C[(size_t)(m+r)*N + n] = f2bf(acc[i][j][r] * scale);
      }
    }
  } else {
    float* C = (float*)Cv + (size_t)z * cbst;
    #pragma unroll
    for (int i=0;i<4;i++){
      int m = mw + i*16;
      #pragma unroll
      for (int j=0;j<4;j++){
        int n = nw + j*16;
        #pragma unroll
        for (int r=0;r<4;r++)
          C[(size_t)(m+r)*N + n] = acc[i][j][r];
      }
    }
  }
}

// ---------------- row softmax, in-place on bf16 scores [rows][2048] ----------------
__global__ __launch_bounds__(256) void softmax_kernel(short* __restrict__ S){
  const int row = blockIdx.x;
  short* p = S + (size_t)row * 2048;
  const int t = threadIdx.x, w = t >> 6, l = t & 63;
  short8 v = *(short8*)&p[t*8];
  float f[8];
  #pragma unroll
  for (int i=0;i<8;i++) f[i] = bf2f(v[i]);
  float mx = f[0];
  #pragma unroll
  for (int i=1;i<8;i++) mx = fmaxf(mx, f[i]);
  #pragma unroll
  for (int off=32; off>=1; off>>=1) mx = fmaxf(mx, __shfl_xor(mx, off));
  __shared__ float rmax[4], rsum[4];
  if (l == 0) rmax[w] = mx;
  __syncthreads();
  mx = fmaxf(fmaxf(rmax[0], rmax[1]), fmaxf(rmax[2], rmax[3]));
  float e[8], s = 0.f;
  #pragma unroll
  for (int i=0;i<8;i++){ e[i] = __expf(f[i] - mx); s += e[i]; }
  #pragma unroll
  for (int off=32; off>=1; off>>=1) s += __shfl_xor(s, off);
  if (l == 0) rsum[w] = s;
  __syncthreads();
  s = rsum[0] + rsum[1] + rsum[2] + rsum[3];
  float inv = 1.0f / s;
  short8 o;
  #pragma unroll
  for (int i=0;i<8;i++) o[i] = f2bf(e[i] * inv);
  *(short8*)&p[t*8] = o;
}

// ---------------- launch ----------------
extern "C" void kernel_launch(void* const* d_in, const int* in_sizes, int n_in,
                              void* d_out, int out_size, void* d_ws, size_t ws_size,
                              hipStream_t stream){
  (void)in_sizes; (void)n_in; (void)out_size; (void)ws_size;
  const float* x  = (const float*)d_in[0];
  const float* Wq = (const float*)d_in[1];
  const float* bq = (const float*)d_in[2];
  const float* Wk = (const float*)d_in[3];
  const float* bk = (const float*)d_in[4];
  const float* Wv = (const float*)d_in[5];
  const float* bv = (const float*)d_in[6];
  float* out = (float*)d_out;
  char* ws = (char*)d_ws;

  // ws layout (bytes): total 148,897,792 (unchanged footprint)
  // [0, 32MiB): xb during QKV phase; then reused as 4-batch scores buffer
  short* xb  = (short*)(ws + 0);           // x bf16            32 MiB
  short* Wt  = (short*)(ws + 33554432);    // Wq/Wk/Wv^T bf16    6 MiB
  short* qb  = (short*)(ws + 39845888);    // q bf16            32 MiB
  short* kb  = (short*)(ws + 73400320);    // k bf16            32 MiB
  short* vt  = (short*)(ws + 106954752);   // v^T bf16 [B][D][S] 32 MiB
  short* Sg  = (short*)(ws + 0);           // 4-batch scores (reuses xb)

  cvt_x_kernel<<<8192, 256, 0, stream>>>(x, xb);
  cvt_w_kernel<<<dim3(32,32,3), dim3(32,8), 0, stream>>>(Wq, Wk, Wv, Wt);

  // q and k: z in {0,1}
  gemm_bt<0><<<dim3(128,8,2), 256, 0, stream>>>(xb, 1024, 0L, Wt, 1024, 1048576L,
                                                qb, 16777216L, bq, bk, 16384, 1024, 1024, 1.f);
  // v, written transposed (reads xb — must precede scores overwriting it)
  gemm_bt<1><<<dim3(128,8,1), 256, 0, stream>>>(xb, 1024, 0L, Wt + 2*1048576, 1024, 0L,
                                                vt, 0L, bv, nullptr, 16384, 1024, 1024, 1.f);

  // attention in 2 groups of 4 batches, z-batched for occupancy
  for (int g = 0; g < 2; g++){
    const size_t boff = (size_t)g * 4 * 2097152;   // 4 batches * S*D elements
    // scores = q_b @ k_b^T * (1/32) -> bf16, z in [0,4)
    gemm_bt<2><<<dim3(16,16,4), 256, 0, stream>>>(qb + boff, 1024, 2097152L,
                                                  kb + boff, 1024, 2097152L,
                                                  Sg, 4194304L, nullptr, nullptr,
                                                  2048, 2048, 1024, 0.03125f);
    softmax_kernel<<<8192, 256, 0, stream>>>(Sg);
    // out_b = P @ v_b  (BT-form against vt), z in [0,4)
    gemm_bt<3><<<dim3(16,8,4), 256, 0, stream>>>(Sg, 2048, 4194304L,
                                                 vt + boff, 2048, 2097152L,
                                                 out + boff, 2097152L, nullptr, nullptr,
                                                 2048, 1024, 2048, 1.f);
  }
}

// Round 5
// 391.331 us; speedup vs baseline: 2.1772x; 1.3105x over previous
//
#include <hip/hip_runtime.h>

typedef __attribute__((ext_vector_type(8))) short short8;
typedef __attribute__((ext_vector_type(4))) short short4v;
typedef __attribute__((ext_vector_type(4))) float f32x4;
typedef unsigned int u32;

#define AS1 __attribute__((address_space(1)))
#define AS3 __attribute__((address_space(3)))

__device__ __forceinline__ short f2bf(float x){
  union { float f; u32 u; } v; v.f = x;
  u32 r = (v.u + 0x7FFFu + ((v.u >> 16) & 1u)) >> 16;   // RNE
  return (short)r;
}
__device__ __forceinline__ float bf2f(short s){
  union { u32 u; float f; } v; v.u = ((u32)(unsigned short)s) << 16;
  return v.f;
}
__device__ __forceinline__ void gload16(const void* src, void* dst){
  __builtin_amdgcn_global_load_lds((const AS1 u32*)src, (AS3 u32*)dst, 16, 0, 0);
}

// ---------------- converts ----------------
__global__ __launch_bounds__(256) void cvt_x_kernel(const float* __restrict__ x, short* __restrict__ xb){
  int i = blockIdx.x * 256 + threadIdx.x;
  if (i >= 2097152) return;
  const float4* xf = (const float4*)x;
  float4 a = xf[2*i], b = xf[2*i+1];
  short8 o;
  o[0]=f2bf(a.x); o[1]=f2bf(a.y); o[2]=f2bf(a.z); o[3]=f2bf(a.w);
  o[4]=f2bf(b.x); o[5]=f2bf(b.y); o[6]=f2bf(b.z); o[7]=f2bf(b.w);
  ((short8*)xb)[i] = o;
}

// transpose-convert W [K=1024][N=1024] f32 -> Wt [N][K] bf16, z selects q/k/v
__global__ __launch_bounds__(256) void cvt_w_kernel(const float* __restrict__ Wq, const float* __restrict__ Wk,
                                                    const float* __restrict__ Wv, short* __restrict__ Wt){
  __shared__ float tile[32][33];
  const float* W = blockIdx.z == 0 ? Wq : (blockIdx.z == 1 ? Wk : Wv);
  short* out = Wt + (size_t)blockIdx.z * 1024 * 1024;
  int n0 = blockIdx.x * 32, k0 = blockIdx.y * 32;
  int tx = threadIdx.x, ty = threadIdx.y;
  #pragma unroll
  for (int i=0;i<4;i++) tile[ty + 8*i][tx] = W[(size_t)(k0 + ty + 8*i) * 1024 + n0 + tx];
  __syncthreads();
  #pragma unroll
  for (int i=0;i<4;i++) out[(size_t)(n0 + ty + 8*i) * 1024 + k0 + tx] = f2bf(tile[tx][ty + 8*i]);
}

// ---------------- 256x256 deep-pipelined BT-form bf16 GEMM ----------------
// C[m][n] = sum_k A[m][k]*B[n][k].  BK=64, 512 thr = 8 waves (2M x 4N),
// per-wave 128x64 output = acc[8][4] f32x4.  LDS 128 KiB (A,B double-buffered).
// T2: read-side XOR swizzle (chunk ^= row&7) with inverse-swizzled global src
//     (linear gload_lds dest — rule #21 both-sides-or-neither).
// T4: counted vmcnt(8) — tile t+1/t+2 loads stay in flight across barriers.
// T5: setprio(1) around the 64-MFMA cluster.
// EPI: 0 = bf16 + bias (q/k via z); 1 = bf16 transposed + bias (v -> vt);
//      2 = bf16 scaled (scores); 3 = f32 (PV -> out). C offset by z*cbst.
template<int EPI>
__global__ __launch_bounds__(512, 2)
void gemm256(const short* __restrict__ A, int lda, long abst,
             const short* __restrict__ B, int ldb, long bbst,
             void* __restrict__ Cv, long cbst,
             const float* __restrict__ bias0, const float* __restrict__ bias1,
             int M, int N, int K, float scale)
{
  __shared__ alignas(16) short As[32768];   // 2 x [256][64] bf16
  __shared__ alignas(16) short Bs[32768];
  const int z = blockIdx.z;
  A += (size_t)z * abst;
  B += (size_t)z * bbst;
  const int m0 = blockIdx.x * 256, n0 = blockIdx.y * 256;
  const int tid = threadIdx.x;
  const int w = tid >> 6, l = tid & 63;
  const int wm = w >> 2, wn = w & 3;            // wave grid 2M x 4N
  const int lr = l & 15, l4 = l >> 4;
  const u32 sw = (u32)(l & 7) << 4;             // swizzle: row&7 == l&7 for frag rows
  const u32 koff0 = ((u32)l4 << 4) ^ sw;        // k-half 0 byte offset (swizzled)
  const u32 koff1 = koff0 ^ 64u;                // k-half 1
  const size_t lda2 = (size_t)lda * 2, ldb2 = (size_t)ldb * 2;

  f32x4 acc[8][4];
  #pragma unroll
  for (int i=0;i<8;i++)
    #pragma unroll
    for (int j=0;j<4;j++) acc[i][j] = (f32x4){0.f,0.f,0.f,0.f};

  // staging: thread -> linear 16B chunk (row = L>>3, chunk = L&7); source chunk
  // inverse-swizzled so LDS linear holds swizzled layout.
  const int r0 = tid >> 3;                       // 0..63
  const int c8 = (tid & 7) ^ (r0 & 7);
  const char* Asrc = (const char*)A + (size_t)(m0 + r0) * lda2 + c8 * 16;
  const char* Bsrc = (const char*)B + (size_t)(n0 + r0) * ldb2 + c8 * 16;
  char* AD = (char*)As + (w * 64) * 16;          // wave-uniform dest base
  char* BD = (char*)Bs + (w * 64) * 16;

  const int NT = K >> 6;

  auto stage = [&](int T, int p){
    const char* aS = Asrc + (size_t)T * 128;     // K-tile byte offset
    const char* bS = Bsrc + (size_t)T * 128;
    char* aD = AD + p * 32768;
    char* bD = BD + p * 32768;
    #pragma unroll
    for (int i = 0; i < 4; i++){                 // 4 chunk-iters x (A,B) = 8 loads
      gload16(aS + (size_t)(i*64) * lda2, aD + i * 8192);
      gload16(bS + (size_t)(i*64) * ldb2, bD + i * 8192);
    }
  };

  stage(0, 0);
  stage(1, 1);

  for (int T = 0; T < NT; T++){
    const int p = T & 1;
    if (T < NT - 1) asm volatile("s_waitcnt vmcnt(8)" ::: "memory");  // tile T landed, T+1 in flight
    else            asm volatile("s_waitcnt vmcnt(0)" ::: "memory");
    __builtin_amdgcn_s_barrier();                // tile T visible to all waves

    const char* aR = (const char*)As + p * 32768 + (wm * 128 + lr) * 128;
    const char* bR = (const char*)Bs + p * 32768 + (wn * 64 + lr) * 128;
    short8 fa[2][8], fb[2][4];
    #pragma unroll
    for (int i = 0; i < 8; i++){
      fa[0][i] = *(const short8*)(aR + i * 2048 + koff0);
      fa[1][i] = *(const short8*)(aR + i * 2048 + koff1);
    }
    #pragma unroll
    for (int j = 0; j < 4; j++){
      fb[0][j] = *(const short8*)(bR + j * 2048 + koff0);
      fb[1][j] = *(const short8*)(bR + j * 2048 + koff1);
    }
    asm volatile("s_waitcnt lgkmcnt(0)" ::: "memory");  // my reads of buf[p] done
    __builtin_amdgcn_s_barrier();                // ALL waves' reads done -> safe to overwrite
    if (T + 2 < NT) stage(T + 2, p);             // DMA overlaps MFMA below

    __builtin_amdgcn_s_setprio(1);
    #pragma unroll
    for (int kh = 0; kh < 2; kh++)
      #pragma unroll
      for (int i = 0; i < 8; i++)
        #pragma unroll
        for (int j = 0; j < 4; j++)
          acc[i][j] = __builtin_amdgcn_mfma_f32_16x16x32_bf16(fa[kh][i], fb[kh][j], acc[i][j], 0, 0, 0);
    __builtin_amdgcn_s_setprio(0);
  }

  // epilogue: C/D layout col = lane&15, row = (lane>>4)*4 + reg  [m89/m91]
  const int mwb = m0 + wm*128 + l4*4;
  const int nwb = n0 + wn*64 + lr;

  if constexpr (EPI == 0){
    const float* bias = z ? bias1 : bias0;
    short* C = (short*)Cv + (size_t)z * cbst;
    float bvv[4];
    #pragma unroll
    for (int j=0;j<4;j++) bvv[j] = bias[nwb + j*16];
    #pragma unroll
    for (int i=0;i<8;i++){
      int m = mwb + i*16;
      #pragma unroll
      for (int j=0;j<4;j++){
        int n = nwb + j*16;
        #pragma unroll
        for (int r=0;r<4;r++)
          C[(size_t)(m+r)*N + n] = f2bf(acc[i][j][r] + bvv[j]);
      }
    }
  } else if constexpr (EPI == 1){
    short* C = (short*)Cv;                       // vt[b][n][m_local], S=2048
    float bvv[4];
    #pragma unroll
    for (int j=0;j<4;j++) bvv[j] = bias0[nwb + j*16];
    #pragma unroll
    for (int i=0;i<8;i++){
      int m = mwb + i*16;
      int bidx = m >> 11, ml = m & 2047;
      #pragma unroll
      for (int j=0;j<4;j++){
        int n = nwb + j*16;
        short4v pk;
        #pragma unroll
        for (int r=0;r<4;r++) pk[r] = f2bf(acc[i][j][r] + bvv[j]);
        *(short4v*)&C[((size_t)(bidx*1024 + n)) * 2048 + ml] = pk;
      }
    }
  } else if constexpr (EPI == 2){
    short* C = (short*)Cv + (size_t)z * cbst;
    #pragma unroll
    for (int i=0;i<8;i++){
      int m = mwb + i*16;
      #pragma unroll
      for (int j=0;j<4;j++){
        int n = nwb + j*16;
        #pragma unroll
        for (int r=0;r<4;r++)
          C[(size_t)(m+r)*N + n] = f2bf(acc[i][j][r] * scale);
      }
    }
  } else {
    float* C = (float*)Cv + (size_t)z * cbst;
    #pragma unroll
    for (int i=0;i<8;i++){
      int m = mwb + i*16;
      #pragma unroll
      for (int j=0;j<4;j++){
        int n = nwb + j*16;
        #pragma unroll
        for (int r=0;r<4;r++)
          C[(size_t)(m+r)*N + n] = acc[i][j][r];
      }
    }
  }
}

// ---------------- row softmax, in-place on bf16 scores [rows][2048] ----------------
__global__ __launch_bounds__(256) void softmax_kernel(short* __restrict__ S){
  const int row = blockIdx.x;
  short* p = S + (size_t)row * 2048;
  const int t = threadIdx.x, w = t >> 6, l = t & 63;
  short8 v = *(short8*)&p[t*8];
  float f[8];
  #pragma unroll
  for (int i=0;i<8;i++) f[i] = bf2f(v[i]);
  float mx = f[0];
  #pragma unroll
  for (int i=1;i<8;i++) mx = fmaxf(mx, f[i]);
  #pragma unroll
  for (int off=32; off>=1; off>>=1) mx = fmaxf(mx, __shfl_xor(mx, off));
  __shared__ float rmax[4], rsum[4];
  if (l == 0) rmax[w] = mx;
  __syncthreads();
  mx = fmaxf(fmaxf(rmax[0], rmax[1]), fmaxf(rmax[2], rmax[3]));
  float e[8], s = 0.f;
  #pragma unroll
  for (int i=0;i<8;i++){ e[i] = __expf(f[i] - mx); s += e[i]; }
  #pragma unroll
  for (int off=32; off>=1; off>>=1) s += __shfl_xor(s, off);
  if (l == 0) rsum[w] = s;
  __syncthreads();
  s = rsum[0] + rsum[1] + rsum[2] + rsum[3];
  float inv = 1.0f / s;
  short8 o;
  #pragma unroll
  for (int i=0;i<8;i++) o[i] = f2bf(e[i] * inv);
  *(short8*)&p[t*8] = o;
}

// ---------------- launch ----------------
extern "C" void kernel_launch(void* const* d_in, const int* in_sizes, int n_in,
                              void* d_out, int out_size, void* d_ws, size_t ws_size,
                              hipStream_t stream){
  (void)in_sizes; (void)n_in; (void)out_size;
  const float* x  = (const float*)d_in[0];
  const float* Wq = (const float*)d_in[1];
  const float* bq = (const float*)d_in[2];
  const float* Wk = (const float*)d_in[3];
  const float* bk = (const float*)d_in[4];
  const float* Wv = (const float*)d_in[5];
  const float* bv = (const float*)d_in[6];
  float* out = (float*)d_out;
  char* ws = (char*)d_ws;

  // ws layout: qb@0 (32M), kb@32M, vt@64M, xb@96M (32M), Wt@128M (6M)
  // scores overlay xb (+Wt if big): small = 32 MiB (z=4 x2), big = 64 MiB (z=8)
  short* qb  = (short*)(ws + 0);
  short* kb  = (short*)(ws + 33554432);
  short* vt  = (short*)(ws + 67108864);
  short* xb  = (short*)(ws + 100663296);
  short* Wt  = (short*)(ws + 134217728);
  short* Sg  = xb;
  const bool big = ws_size >= (size_t)167772160;   // 160 MiB

  cvt_x_kernel<<<8192, 256, 0, stream>>>(x, xb);
  cvt_w_kernel<<<dim3(32,32,3), dim3(32,8), 0, stream>>>(Wq, Wk, Wv, Wt);

  // q and k: z in {0,1} (qb/kb adjacent: cbst = 16M shorts)
  gemm256<0><<<dim3(64,4,2), 512, 0, stream>>>(xb, 1024, 0L, Wt, 1024, 1048576L,
                                               qb, 16777216L, bq, bk, 16384, 1024, 1024, 1.f);
  // v, written transposed
  gemm256<1><<<dim3(64,4,1), 512, 0, stream>>>(xb, 1024, 0L, Wt + 2*1048576, 1024, 0L,
                                               vt, 0L, bv, nullptr, 16384, 1024, 1024, 1.f);

  if (big){
    gemm256<2><<<dim3(8,8,8), 512, 0, stream>>>(qb, 1024, 2097152L, kb, 1024, 2097152L,
                                                Sg, 4194304L, nullptr, nullptr,
                                                2048, 2048, 1024, 0.03125f);
    softmax_kernel<<<16384, 256, 0, stream>>>(Sg);
    gemm256<3><<<dim3(8,4,8), 512, 0, stream>>>(Sg, 2048, 4194304L, vt, 2048, 2097152L,
                                                out, 2097152L, nullptr, nullptr,
                                                2048, 1024, 2048, 1.f);
  } else {
    for (int g = 0; g < 2; g++){
      const size_t boff = (size_t)g * 4 * 2097152;
      gemm256<2><<<dim3(8,8,4), 512, 0, stream>>>(qb + boff, 1024, 2097152L,
                                                  kb + boff, 1024, 2097152L,
                                                  Sg, 4194304L, nullptr, nullptr,
                                                  2048, 2048, 1024, 0.03125f);
      softmax_kernel<<<8192, 256, 0, stream>>>(Sg);
      gemm256<3><<<dim3(8,4,4), 512, 0, stream>>>(Sg, 2048, 4194304L,
                                                  vt + boff, 2048, 2097152L,
                                                  out + boff, 2097152L, nullptr, nullptr,
                                                  2048, 1024, 2048, 1.f);
    }
  }
}